// Round 22
// baseline (83.598 us; speedup 1.0000x reference)
//
#include <hip/hip_runtime.h>
#include <math.h>

#define PH 7
#define PW 7
#define B_ 4
#define C_ 256
#define H_ 50
#define W_ 50
#define R_ 256
#define S_ (H_ * W_)     // 2500
#define NCELL (PH * PW)  // 49
#define SSTR 65          // strip row stride: (p*65)%32 = p -> distinct banks
#define NBLK (R_ * 16)   // 4096 blocks
#define NF4  (B_ * C_ * S_ / 4)   // 640,000 float4 = whole features array

// SINGLE dispatch, direct (B,C,H,W). R20 (measured best, 81.35) + issue-early
// LLC-warming prefetch. REP arithmetic (R18/R19): warm rep = 15.4 us, cold
// single rep = 30.8 -> ~15 us of the kernel is first-touch HBM misses (the
// harness's 256 MiB fill sweeps LLC every iteration, so features are ALWAYS
// cold). Demand misses are <=200 B roi-row segments (latency-bound, ~900 cy);
// a linear 10.24 MB sweep at kernel start fetches the same bytes at full BW
// (~1.6 us aggregate). Consume is deferred to kernel end (asm keep-alive) so
// no waitcnt enters the early critical path — loads fly while rois decode.
// Pool structure byte-identical to R20: adaptive 4/2/1-ch packing, paired-
// band walk (4 loads in flight), stride-65 strip, scalar bounds, clamped
// dup cols, lgkmcnt+sched_barrier fences, 196 B contiguous stores.
__global__ void __launch_bounds__(256, 8)
roi_pool_pack4(const float* __restrict__ features, const int* __restrict__ rois,
               float* __restrict__ out) {
    __shared__ float strip[4][PH][SSTR];  // wave-private strips, 7280 B
    const int bx   = blockIdx.x;
    const int r    = bx >> 4;             // 0..255
    const int wid  = threadIdx.x >> 6;    // 0..3
    const int lane = threadIdx.x & 63;
    const int cw   = ((bx & 15) << 4) | (wid << 2);   // wave's 4-ch base

    // ---- prefetch: 1 coalesced float4/thread, linear over features ----
    // (issued now, consumed at kernel end -> warms LLC under the pooling)
    float4 pf = make_float4(0.f, 0.f, 0.f, 0.f);
    {
        const int gtid = bx * 256 + threadIdx.x;      // 0..1,048,575
        if (gtid < NF4)                                // blocks >=2500 skip
            pf = ((const float4*)features)[gtid];
    }

    const int* roi = rois + r * 5;        // r uniform -> scalar loads
    const int b  = roi[0];
    const int x1 = roi[1] >> 4;           // floor(v/16), v in [0,800)
    const int y1 = roi[2] >> 4;
    const int x2 = roi[3] >> 4;
    const int y2 = roi[4] >> 4;
    const int h = y2 - y1 + 1;            // 1..50
    const int w = x2 - x1 + 1;            // 1..50

    // adaptive packing (all wave-uniform scalars)
    const int npacksh = (w <= 16) ? 2 : (w <= 32) ? 1 : 0;
    const int npack   = 1 << npacksh;     // 4 / 2 / 1 channels per pass
    const int ncolsh  = 6 - npacksh;      // 16 / 32 / 64 cols per channel
    const int ncol    = 1 << ncolsh;
    const int passes  = 4 >> npacksh;     // 1 / 2 / 4

    const int hc   = lane >> ncolsh;      // sub-channel within pass
    const int col  = lane & (ncol - 1);
    const int xcol = x1 + min(col, w - 1);   // clamped dup: max-safe, merged

    // reduce-phase lane mapping (lanes 49..63 idle there)
    const int cell = (lane < NCELL) ? lane : NCELL - 1;
    const int p  = cell / PW;             // magic mul
    const int q  = cell - p * PW;
    const int swr  = (q * w) / PW;
    const int ewr  = ((q + 1) * w + PW - 1) / PW;
    const int kwm1 = ewr - swr - 1;       // >= 0
    const int kmax = w / PW + 2;          // scalar bound, covers all windows

    #pragma unroll 1
    for (int pi = 0; pi < passes; ++pi) {
        const int chb = cw + (pi << npacksh);      // pass channel base
        const float* pl = features + ((size_t)b * C_ + chb + hc) * S_;

        float cm[PH];

        // paired bands (pA,pB): 4 independent loads in flight per iteration
        #pragma unroll
        for (int pb = 0; pb < 3; ++pb) {
            const int pA = 2 * pb, pB = 2 * pb + 1;
            const int shA = y1 + (pA * h) / PH;
            const int nA  = y1 + ((pA + 1) * h + PH - 1) / PH - shA;  // >=1
            const int shB = y1 + (pB * h) / PH;
            const int nB  = y1 + ((pB + 1) * h + PH - 1) / PH - shB;  // >=1
            const int n   = max(nA, nB);           // nA,nB differ by <=1
            const float* rA = pl + shA * W_ + xcol;
            const float* rB = pl + shB * W_ + xcol;
            float cA = -INFINITY, cB = -INFINITY;
            int i = 0;
            if (n & 1) {                           // row 0 valid for both
                cA = fmaxf(cA, rA[0]);
                cB = fmaxf(cB, rB[0]);
                ++i;
            }
            for (; i < n; i += 2) {                // scalar row clamps
                const float a0 = rA[min(i,     nA - 1) * W_];
                const float a1 = rA[min(i + 1, nA - 1) * W_];
                const float b0 = rB[min(i,     nB - 1) * W_];
                const float b1 = rB[min(i + 1, nB - 1) * W_];
                cA = fmaxf(cA, fmaxf(a0, a1));
                cB = fmaxf(cB, fmaxf(b0, b1));
            }
            cm[pA] = cA; cm[pB] = cB;
        }
        {   // band 6 alone (2-row steps, proven loop)
            const int sh = y1 + (6 * h) / PH;
            const int eh = y1 + h;                 // y2+1
            const float* prow = pl + sh * W_ + xcol;
            int n = eh - sh;
            float c6 = -INFINITY;
            if (n & 1) { c6 = fmaxf(c6, *prow); prow += W_; --n; }
            for (; n > 0; n -= 2, prow += 2 * W_)
                c6 = fmaxf(c6, fmaxf(prow[0], prow[W_]));
            cm[6] = c6;
        }

        #pragma unroll
        for (int pp = 0; pp < PH; ++pp)            // lane-linear: 2-way, free
            strip[wid][pp][lane] = cm[pp];
        asm volatile("s_waitcnt lgkmcnt(0)" ::: "memory");   // cross-lane RAW
        __builtin_amdgcn_sched_barrier(0);         // rule-18 fence

        #pragma unroll
        for (int hc2 = 0; hc2 < 4; ++hc2) {        // reduce pass channels
            if (hc2 < npack && lane < NCELL) {
                const float* cb2 = &strip[wid][p][(hc2 << ncolsh) + swr];
                float m = -INFINITY;
                for (int k = 0; k < kmax; ++k)     // scalar bound, clamped
                    m = fmaxf(m, cb2[min(k, kwm1)]);
                out[((size_t)r * C_ + chb + hc2) * NCELL + lane] = m;
            }
        }
        // keep next pass's strip writes after this pass's reads
        asm volatile("" ::: "memory");
        __builtin_amdgcn_sched_barrier(0);
    }

    // consume the prefetch values LAST: keeps the loads live (rule 17)
    // without ever stalling the hot path on their completion.
    asm volatile("" :: "v"(pf.x), "v"(pf.y), "v"(pf.z), "v"(pf.w));
}

extern "C" void kernel_launch(void* const* d_in, const int* in_sizes, int n_in,
                              void* d_out, int out_size, void* d_ws, size_t ws_size,
                              hipStream_t stream) {
    const float* features = (const float*)d_in[0];
    const int*   rois     = (const int*)d_in[1];
    float*       out      = (float*)d_out;
    (void)d_ws; (void)ws_size;

    roi_pool_pack4<<<NBLK, 256, 0, stream>>>(features, rois, out);
}